// Round 6
// baseline (552.066 us; speedup 1.0000x reference)
//
#include <hip/hip_runtime.h>
#include <math.h>

#define HDIM 256
#define NSTATE 64
#define NDEPTH 4
#define LSEQ 2048
#define NBATCH 8
#define NROWS (NBATCH*LSEQ)   // 16384
#define HN (HDIM*NSTATE)      // 16384
#define INDIM 51
#define OUTC 204
#define M1 (256*4096)         // shorts per variant (256 h x 64x64)

typedef short bfrag8 __attribute__((ext_vector_type(8)));
typedef float facc4 __attribute__((ext_vector_type(4)));

// ---------------- helpers ----------------
template<int CTRL>
__device__ __forceinline__ float dpp_add(float x) {
  int y = __builtin_amdgcn_update_dpp(0, __float_as_int(x), CTRL, 0xf, 0xf, true);
  return x + __int_as_float(y);
}
__device__ __forceinline__ float wave_sum64(float x) {
  x = dpp_add<0x111>(x);
  x = dpp_add<0x112>(x);
  x = dpp_add<0x114>(x);
  x = dpp_add<0x118>(x);
  x = dpp_add<0x142>(x);
  x = dpp_add<0x143>(x);
  return x;   // total in lane 63
}
__device__ __forceinline__ float rdlane(float v, int lane) {
  return __int_as_float(__builtin_amdgcn_readlane(__float_as_int(v), lane));
}
__device__ __forceinline__ float gelu_tanh(float x) {
  float x3 = x*x*x;
  return 0.5f*x*(1.f + tanhf(0.7978845608028654f*(x + 0.044715f*x3)));
}
__device__ __forceinline__ unsigned short f2bf(float x) {
  unsigned u = __float_as_uint(x);
  unsigned r = (u + 0x7FFFu + ((u >> 16) & 1u)) >> 16;
  return (unsigned short)r;
}
__device__ __forceinline__ float bf2f(unsigned short h) {
  return __uint_as_float(((unsigned)h) << 16);
}
__device__ __forceinline__ bfrag8 mk8(unsigned a, unsigned b, unsigned c, unsigned d) {
  union { unsigned u[4]; bfrag8 f; } U;
  U.u[0]=a; U.u[1]=b; U.u[2]=c; U.u[3]=d; return U.f;
}
__device__ __forceinline__ unsigned long long pk4(unsigned short a,unsigned short b,
                                                  unsigned short c,unsigned short d){
  return (unsigned long long)a | ((unsigned long long)b<<16) |
         ((unsigned long long)c<<32) | ((unsigned long long)d<<48);
}

// ---------------- input projection: x[16384,51] @ w[51,256] + b -> u fp32 + uth/utl splits
__global__ __launch_bounds__(256) void proj_kernel(
    const float* __restrict__ x, const float* __restrict__ w,
    const float* __restrict__ bias, float* __restrict__ u,
    unsigned short* __restrict__ uth, unsigned short* __restrict__ utl) {
  __shared__ float xs[8][52];
  const int r0 = blockIdx.x * 8;
  const int tid = threadIdx.x;
  for (int idx = tid; idx < 8*INDIM; idx += 256) {
    int rr = idx / INDIM, k = idx % INDIM;
    xs[rr][k] = x[(size_t)(r0+rr)*INDIM + k];
  }
  __syncthreads();
  const int hcol = tid;
  float acc[8];
  const float bb = bias[hcol];
#pragma unroll
  for (int rr = 0; rr < 8; ++rr) acc[rr] = bb;
#pragma unroll
  for (int k = 0; k < 48; k += 4) {
    float w0 = w[(k+0)*HDIM + hcol];
    float w1 = w[(k+1)*HDIM + hcol];
    float w2 = w[(k+2)*HDIM + hcol];
    float w3 = w[(k+3)*HDIM + hcol];
#pragma unroll
    for (int rr = 0; rr < 8; ++rr) {
      float4 xv = *(const float4*)&xs[rr][k];
      acc[rr] = fmaf(xv.x, w0, acc[rr]);
      acc[rr] = fmaf(xv.y, w1, acc[rr]);
      acc[rr] = fmaf(xv.z, w2, acc[rr]);
      acc[rr] = fmaf(xv.w, w3, acc[rr]);
    }
  }
#pragma unroll
  for (int k = 48; k < INDIM; ++k) {
    float wk = w[k*HDIM + hcol];
#pragma unroll
    for (int rr = 0; rr < 8; ++rr) acc[rr] = fmaf(xs[rr][k], wk, acc[rr]);
  }
  unsigned short sh[8], sl[8];
#pragma unroll
  for (int rr = 0; rr < 8; ++rr) {
    u[(size_t)(r0+rr)*HDIM + hcol] = acc[rr];
    unsigned short hh = f2bf(acc[rr]);
    sh[rr] = hh; sl[rr] = f2bf(acc[rr] - bf2f(hh));
  }
  const int b = r0 >> 11, lw = r0 & 2047;
  size_t ob = ((size_t)(b*HDIM + hcol))*LSEQ + lw;
  *(unsigned long long*)&uth[ob]   = pk4(sh[0],sh[1],sh[2],sh[3]);
  *(unsigned long long*)&uth[ob+4] = pk4(sh[4],sh[5],sh[6],sh[7]);
  *(unsigned long long*)&utl[ob]   = pk4(sl[0],sl[1],sl[2],sl[3]);
  *(unsigned long long*)&utl[ob+4] = pk4(sl[4],sl[5],sl[6],sl[7]);
}

// ---------------- build per-layer matrices into fragment-tiled global buffers
// mats layout (shorts): E2 v=0..3 at v*M1 ; Epow v=0..3 at (4+v)*M1 ; T v=0..1 at (8+v)*M1
// tile addr within a 64x64 matrix: ((row>>4)*2 + (k>>5))*512 + (row&15)*32 + (k&31)
__device__ __forceinline__ void copy_mats4(const unsigned short (*BB)[64][68],
    unsigned short* dst, int h, int tid) {
#pragma unroll
  for (int v = 0; v < 4; ++v) {
    unsigned int* dv = (unsigned int*)(dst + (size_t)v*M1 + (size_t)h*4096);
    for (int uu = tid; uu < 2048; uu += 256) {
      int toff = uu*2;
      int tile = toff >> 9, win = toff & 511;
      int row = (tile>>1)*16 + (win>>5);
      int k   = (tile&1)*32 + (win&31);
      dv[uu] = *(const unsigned int*)&BB[v][row][k];
    }
  }
}

__global__ __launch_bounds__(256) void build_mats(
    const float* __restrict__ log_dt, const float* __restrict__ lAr,
    const float* __restrict__ Aim, const float* __restrict__ Cre,
    const float* __restrict__ Cim, const float* __restrict__ Dv,
    unsigned short* __restrict__ mats, float* __restrict__ coef) {
  __shared__ unsigned short BB[4][64][68];
  __shared__ float kvs[64];
  const int h = blockIdx.x;
  const int tid = threadIdx.x;
  const int w = tid >> 6, l = tid & 63;
  const int i0 = h*64 + l;
  float dt = expf(log_dt[h]);
  float Ar = -expf(lAr[i0]);
  float Ai = Aim[i0];
  float e  = expf(Ar*dt);
  float ar = e * cosf(Ai*dt), ai = e * sinf(Ai*dt);
  float inv = 1.f/(Ar*Ar + Ai*Ai);
  float nre = ar - 1.f, nim = ai;
  float qre = (nre*Ar + nim*Ai)*inv;
  float qim = (nim*Ar - nre*Ai)*inv;
  float cre0 = Cre[i0], cim0 = Cim[i0];
  float cr = 2.f*(cre0*qre - cim0*qim);
  float ci = 2.f*(cre0*qim + cim0*qre);
  float Dh = Dv[h];
  // powers of a
  float a2r = ar*ar - ai*ai,     a2i = 2.f*ar*ai;
  float a4r = a2r*a2r - a2i*a2i, a4i = 2.f*a2r*a2i;
  float a8r = a4r*a4r - a4i*a4i, a8i = 2.f*a4r*a4i;
  float a16r= a8r*a8r - a8i*a8i, a16i= 2.f*a8r*a8i;
  float a32r= a16r*a16r - a16i*a16i, a32i = 2.f*a16r*a16i;
  float a48r= a32r*a16r - a32i*a16i, a48i = a32r*a16i + a32i*a16r;
  float a64r= a32r*a32r - a32i*a32i, a64i = 2.f*a32r*a32i;
  if (w == 0) {
    coef[0*HN + i0] = a64r; coef[1*HN + i0] = a64i;
    coef[2*HN + i0] = cr;   coef[3*HN + i0] = ci;
  }
  // kv: wave w handles m in [16w,16w+16)
  {
    float br, bi2;
    if      (w == 0) { br = 1.f;  bi2 = 0.f;  }
    else if (w == 1) { br = a16r; bi2 = a16i; }
    else if (w == 2) { br = a32r; bi2 = a32i; }
    else             { br = a48r; bi2 = a48i; }
    float tr = cr*br - ci*bi2, ti = cr*bi2 + ci*br;
#pragma unroll
    for (int mm = 0; mm < 16; ++mm) {
      float s = wave_sum64(tr);
      if (l == 63) kvs[16*w + mm] = s;
      float nr = tr*ar - ti*ai, ni = tr*ai + ti*ar;
      tr = nr; ti = ni;
    }
  }
  // E2[n=l][j] = a^{63-j}; wave w covers j in [16w,16w+16), descending
  {
    float pr, pi;
    if      (w == 3) { pr = 1.f;  pi = 0.f;  }
    else if (w == 2) { pr = a16r; pi = a16i; }
    else if (w == 1) { pr = a32r; pi = a32i; }
    else             { pr = a48r; pi = a48i; }
    for (int j = 16*w+15; j >= 16*w; --j) {
      unsigned short hh = f2bf(pr);
      BB[0][l][j] = hh; BB[1][l][j] = f2bf(pr - bf2f(hh));
      hh = f2bf(pi);
      BB[2][l][j] = hh; BB[3][l][j] = f2bf(pi - bf2f(hh));
      float nr = pr*ar - pi*ai, ni = pr*ai + pi*ar;
      pr = nr; pi = ni;
    }
  }
  __syncthreads();
  copy_mats4(BB, mats, h, tid);
  __syncthreads();
  // Epow[t][n=l] = a^{t+1}, imaginary part negated
  {
    float pr, pi;
    if      (w == 0) { pr = ar; pi = ai; }
    else if (w == 1) { pr = a16r*ar - a16i*ai; pi = a16r*ai + a16i*ar; }
    else if (w == 2) { pr = a32r*ar - a32i*ai; pi = a32r*ai + a32i*ar; }
    else             { pr = a48r*ar - a48i*ai; pi = a48r*ai + a48i*ar; }
    for (int t = 16*w; t < 16*w+16; ++t) {
      unsigned short hh = f2bf(pr);
      BB[0][t][l] = hh; BB[1][t][l] = f2bf(pr - bf2f(hh));
      float nv = -pi;
      hh = f2bf(nv);
      BB[2][t][l] = hh; BB[3][t][l] = f2bf(nv - bf2f(hh));
      float nr = pr*ar - pi*ai, ni = pr*ai + pi*ar;
      pr = nr; pi = ni;
    }
  }
  __syncthreads();
  copy_mats4(BB, mats + (size_t)4*M1, h, tid);
  // T[t][j] = k_{t-j} (t>=j) + Dh on diagonal, written straight to global (tiled order)
  for (int idx = tid; idx < 4096; idx += 256) {
    int tile = idx >> 9, win = idx & 511;
    int row = (tile>>1)*16 + (win>>5);
    int jj  = (tile&1)*32 + (win&31);
    int dm = row - jj;
    float v = 0.f;
    if (dm >= 0) v = kvs[dm] + (dm == 0 ? Dh : 0.f);
    unsigned short hh = f2bf(v);
    mats[(size_t)8*M1 + (size_t)h*4096 + idx] = hh;
    mats[(size_t)9*M1 + (size_t)h*4096 + idx] = f2bf(v - bf2f(hh));
  }
}

// ---------------- lean MFMA scan: block = (h, batch-pair), 64 cols = 32 chunks x 2 batches
__device__ __forceinline__ void gemm_conv(facc4 (&acc)[4],
    const unsigned short* __restrict__ uth, const unsigned short* __restrict__ utl,
    const unsigned short* __restrict__ tmat, int h, int bp, int w, int l) {
#pragma unroll
  for (int kb = 0; kb < 2; ++kb) {
    int bo = (w*2+kb)*512 + (l&15)*32 + (l>>4)*8;
    bfrag8 bth = *(const bfrag8*)&tmat[bo];
    bfrag8 btl = *(const bfrag8*)&tmat[M1 + bo];
#pragma unroll
    for (int mt = 0; mt < 4; ++mt) {
      int arow = 16*mt + (l&15);
      size_t ua = ((size_t)((2*bp + (arow>>5))*HDIM + h))*LSEQ + (size_t)(arow&31)*64 + kb*32 + (l>>4)*8;
      bfrag8 ah = *(const bfrag8*)&uth[ua];
      bfrag8 al = *(const bfrag8*)&utl[ua];
      acc[mt] = __builtin_amdgcn_mfma_f32_16x16x32_bf16(ah, bth, acc[mt], 0,0,0);
      acc[mt] = __builtin_amdgcn_mfma_f32_16x16x32_bf16(al, bth, acc[mt], 0,0,0);
      acc[mt] = __builtin_amdgcn_mfma_f32_16x16x32_bf16(ah, btl, acc[mt], 0,0,0);
    }
  }
}

__global__ __launch_bounds__(256) void scan_gemm(
    const unsigned short* __restrict__ uth, const unsigned short* __restrict__ utl,
    const unsigned short* __restrict__ mats, const float* __restrict__ coef,
    float* __restrict__ zt) {
  __shared__ unsigned int SM[2][64][68];   // f32 s_end, then packed bf16-split w
  const int h = blockIdx.x, bp = blockIdx.y;
  const int tid = threadIdx.x, w = tid >> 6, l = tid & 63;

  // ---- GEMM-A: s_end[col][n]
  {
    facc4 are[4], aim[4];
#pragma unroll
    for (int mt = 0; mt < 4; ++mt) { are[mt] = (facc4){0.f,0.f,0.f,0.f}; aim[mt] = (facc4){0.f,0.f,0.f,0.f}; }
    const unsigned short* e2 = mats + (size_t)h*4096;
#pragma unroll
    for (int kb = 0; kb < 2; ++kb) {
      int bo = (w*2+kb)*512 + (l&15)*32 + (l>>4)*8;
      bfrag8 brh = *(const bfrag8*)&e2[(size_t)0*M1 + bo];
      bfrag8 brl = *(const bfrag8*)&e2[(size_t)1*M1 + bo];
      bfrag8 bih = *(const bfrag8*)&e2[(size_t)2*M1 + bo];
      bfrag8 bil = *(const bfrag8*)&e2[(size_t)3*M1 + bo];
#pragma unroll
      for (int mt = 0; mt < 4; ++mt) {
        int arow = 16*mt + (l&15);
        size_t ua = ((size_t)((2*bp + (arow>>5))*HDIM + h))*LSEQ + (size_t)(arow&31)*64 + kb*32 + (l>>4)*8;
        bfrag8 ah = *(const bfrag8*)&uth[ua];
        bfrag8 al = *(const bfrag8*)&utl[ua];
        are[mt] = __builtin_amdgcn_mfma_f32_16x16x32_bf16(ah, brh, are[mt], 0,0,0);
        are[mt] = __builtin_amdgcn_mfma_f32_16x16x32_bf16(al, brh, are[mt], 0,0,0);
        are[mt] = __builtin_amdgcn_mfma_f32_16x16x32_bf16(ah, brl, are[mt], 0,0,0);
        aim[mt] = __builtin_amdgcn_mfma_f32_16x16x32_bf16(ah, bih, aim[mt], 0,0,0);
        aim[mt] = __builtin_amdgcn_mfma_f32_16x16x32_bf16(al, bih, aim[mt], 0,0,0);
        aim[mt] = __builtin_amdgcn_mfma_f32_16x16x32_bf16(ah, bil, aim[mt], 0,0,0);
      }
    }
#pragma unroll
    for (int mt = 0; mt < 4; ++mt)
#pragma unroll
      for (int r = 0; r < 4; ++r) {
        int colg = 16*mt + 4*(l>>4) + r;
        int ng   = 16*w + (l&15);
        ((float*)&SM[0][0][0])[colg*68 + ng] = are[mt][r];
        ((float*)&SM[1][0][0])[colg*68 + ng] = aim[mt][r];
      }
  }
  __syncthreads();

  facc4 acc[4];
#pragma unroll
  for (int mt = 0; mt < 4; ++mt) acc[mt] = (facc4){0.f,0.f,0.f,0.f};
  const unsigned short* tmat = mats + (size_t)8*M1 + (size_t)h*4096;

  if (w < 2) {
    // serial chunk-state combine for batch w; packs w-splits in place
    const int i0 = h*64 + l;
    float a64r = coef[0*HN+i0], a64i = coef[1*HN+i0];
    float cr = coef[2*HN+i0],   ci = coef[3*HN+i0];
    float rr = 0.f, ri = 0.f;
    float* pre = (float*)&SM[0][0][0];
    float* pim = (float*)&SM[1][0][0];
    for (int c = 0; c < 32; ++c) {
      int off = (w*32 + c)*68 + l;
      float tre = pre[off], tim = pim[off];
      float wre = cr*rr - ci*ri;
      float wim = cr*ri + ci*rr;
      unsigned short hh = f2bf(wre);
      unsigned short lo = f2bf(wre - bf2f(hh));
      ((unsigned int*)pre)[off] = (unsigned)hh | ((unsigned)lo << 16);
      hh = f2bf(wim); lo = f2bf(wim - bf2f(hh));
      ((unsigned int*)pim)[off] = (unsigned)hh | ((unsigned)lo << 16);
      float nr = a64r*rr - a64i*ri + tre;
      float ni = a64r*ri + a64i*rr + tim;
      rr = nr; ri = ni;
    }
  } else {
    gemm_conv(acc, uth, utl, tmat, h, bp, w, l);   // waves 2,3 overlap the combine
  }
  __syncthreads();
  if (w < 2) gemm_conv(acc, uth, utl, tmat, h, bp, w, l);

  // ---- GEMM-B: correction, A = packed w from LDS, B = Epow from global
  {
    const unsigned short* ep = mats + (size_t)4*M1 + (size_t)h*4096;
#pragma unroll
    for (int kb = 0; kb < 2; ++kb) {
      int bo = (w*2+kb)*512 + (l&15)*32 + (l>>4)*8;
      bfrag8 erh = *(const bfrag8*)&ep[(size_t)0*M1 + bo];
      bfrag8 erl = *(const bfrag8*)&ep[(size_t)1*M1 + bo];
      bfrag8 eih = *(const bfrag8*)&ep[(size_t)2*M1 + bo];
      bfrag8 eil = *(const bfrag8*)&ep[(size_t)3*M1 + bo];
#pragma unroll
      for (int mt = 0; mt < 4; ++mt) {
        int arow = 16*mt + (l&15);
        int ko = kb*32 + (l>>4)*8;
        const unsigned int* p0 = &SM[0][0][0] + arow*68 + ko;
        const unsigned int* p1 = &SM[1][0][0] + arow*68 + ko;
        uint4 q0 = *(const uint4*)p0;
        uint4 q1 = *(const uint4*)(p0 + 4);
        uint4 s0 = *(const uint4*)p1;
        uint4 s1 = *(const uint4*)(p1 + 4);
        bfrag8 wrh = mk8((q0.x&0xffffu)|(q0.y<<16), (q0.z&0xffffu)|(q0.w<<16),
                         (q1.x&0xffffu)|(q1.y<<16), (q1.z&0xffffu)|(q1.w<<16));
        bfrag8 wrl = mk8((q0.x>>16)|(q0.y&0xffff0000u), (q0.z>>16)|(q0.w&0xffff0000u),
                         (q1.x>>16)|(q1.y&0xffff0000u), (q1.z>>16)|(q1.w&0xffff0000u));
        bfrag8 wih = mk8((s0.x&0xffffu)|(s0.y<<16), (s0.z&0xffffu)|(s0.w<<16),
                         (s1.x&0xffffu)|(s1.y<<16), (s1.z&0xffffu)|(s1.w<<16));
        bfrag8 wil = mk8((s0.x>>16)|(s0.y&0xffff0000u), (s0.z>>16)|(s0.w&0xffff0000u),
                         (s1.x>>16)|(s1.y&0xffff0000u), (s1.z>>16)|(s1.w&0xffff0000u));
        acc[mt] = __builtin_amdgcn_mfma_f32_16x16x32_bf16(wrh, erh, acc[mt], 0,0,0);
        acc[mt] = __builtin_amdgcn_mfma_f32_16x16x32_bf16(wrl, erh, acc[mt], 0,0,0);
        acc[mt] = __builtin_amdgcn_mfma_f32_16x16x32_bf16(wrh, erl, acc[mt], 0,0,0);
        acc[mt] = __builtin_amdgcn_mfma_f32_16x16x32_bf16(wih, eih, acc[mt], 0,0,0);
        acc[mt] = __builtin_amdgcn_mfma_f32_16x16x32_bf16(wil, eih, acc[mt], 0,0,0);
        acc[mt] = __builtin_amdgcn_mfma_f32_16x16x32_bf16(wih, eil, acc[mt], 0,0,0);
      }
    }
  }
  // ---- epilogue
  const int tg = 16*w + (l&15);
#pragma unroll
  for (int mt = 0; mt < 4; ++mt)
#pragma unroll
    for (int r = 0; r < 4; ++r) {
      int colg = 16*mt + 4*(l>>4) + r;
      zt[((size_t)((2*bp + (colg>>5))*HDIM + h))*LSEQ + (size_t)(colg&31)*64 + tg] =
          gelu_tanh(acc[mt][r]);
    }
}

// ---------------- zt [b,h,l] fp32 -> z splits [b,l,h] bf16
__global__ void tsplit_kernel(const float* __restrict__ in,
    unsigned short* __restrict__ oh, unsigned short* __restrict__ ol) {
  __shared__ float tile[32][33];
  int b = blockIdx.z, l0 = blockIdx.x*32, h0 = blockIdx.y*32;
  int tx = threadIdx.x, ty = threadIdx.y;   // (32,8)
#pragma unroll
  for (int i = 0; i < 32; i += 8)
    tile[ty+i][tx] = in[((size_t)(b*HDIM + h0+ty+i))*LSEQ + l0+tx];
  __syncthreads();
#pragma unroll
  for (int i = 0; i < 32; i += 8) {
    float v = tile[tx][ty+i];
    size_t o = ((size_t)(b*LSEQ + l0+ty+i))*HDIM + h0+tx;
    unsigned short hh = f2bf(v);
    oh[o] = hh; ol[o] = f2bf(v - bf2f(hh));
  }
}

// ---------------- GLU: u += act(z@W) with 3-term split-bf16 MFMA, no LDS staging
__global__ __launch_bounds__(256) void glu_mfma(
    const unsigned short* __restrict__ zh, const unsigned short* __restrict__ zl,
    const unsigned short* __restrict__ wgh, const unsigned short* __restrict__ wgl,
    const float* __restrict__ bias, float* __restrict__ u,
    unsigned short* __restrict__ uth, unsigned short* __restrict__ utl) {
  __shared__ float TT[64][68];
  const int bx = blockIdx.x, by = blockIdx.y;
  const int tid = threadIdx.x, w = tid >> 6, l = tid & 63;
  facc4 acc[8];
#pragma unroll
  for (int nf = 0; nf < 8; ++nf) acc[nf] = (facc4){0.f,0.f,0.f,0.f};
  const int m0 = bx*64 + 16*w;
#pragma unroll
  for (int k0 = 0; k0 < HDIM; k0 += 32) {
    int ko = k0 + (l>>4)*8;
    size_t aaddr = (size_t)(m0 + (l&15))*HDIM + ko;
    bfrag8 ah = *(const bfrag8*)&zh[aaddr];
    bfrag8 al = *(const bfrag8*)&zl[aaddr];
#pragma unroll
    for (int nf = 0; nf < 8; ++nf) {
      int nrow = by*64 + 16*(nf&3) + (l&15) + ((nf>=4)?256:0);
      size_t baddr = (size_t)nrow*HDIM + ko;
      bfrag8 bh = *(const bfrag8*)&wgh[baddr];
      bfrag8 bl = *(const bfrag8*)&wgl[baddr];
      acc[nf] = __builtin_amdgcn_mfma_f32_16x16x32_bf16(ah, bh, acc[nf], 0,0,0);
      acc[nf] = __builtin_amdgcn_mfma_f32_16x16x32_bf16(al, bh, acc[nf], 0,0,0);
      acc[nf] = __builtin_amdgcn_mfma_f32_16x16x32_bf16(ah, bl, acc[nf], 0,0,0);
    }
  }
  const int b  = (bx*64) >> 11;
  const int l0 = (bx*64) & 2047;
#pragma unroll
  for (int nf = 0; nf < 4; ++nf) {
    int c = by*64 + 16*nf + (l&15);
#pragma unroll
    for (int r = 0; r < 4; ++r) {
      int m = 16*w + 4*(l>>4) + r;
      int row = bx*64 + m;
      float av = acc[nf][r] + bias[c];
      float gv = acc[nf+4][r] + bias[256 + c];
      float val = u[(size_t)row*HDIM + c] + av * (1.f/(1.f + expf(-gv)));
      u[(size_t)row*HDIM + c] = val;
      TT[16*nf + (l&15)][m] = val;
    }
  }
  __syncthreads();
  {
    int cc = tid >> 2, mq = (tid & 3) * 16;
    int hcol = by*64 + cc;
    size_t ob = ((size_t)(b*HDIM + hcol))*LSEQ + l0 + mq;
#pragma unroll
    for (int q = 0; q < 16; ++q) {
      float v = TT[cc][mq + q];
      unsigned short hh = f2bf(v);
      uth[ob + q] = hh;
      utl[ob + q] = f2bf(v - bf2f(hh));
    }
  }
}

// ---------------- LayerNorm -> split-bf16 un
__global__ __launch_bounds__(256) void ln_kernel(
    const float* __restrict__ u, const float* __restrict__ g,
    const float* __restrict__ b, unsigned short* __restrict__ unh,
    unsigned short* __restrict__ unl) {
  const int r0 = blockIdx.x * 8;
  const int w = threadIdx.x >> 6;
  const int lane = threadIdx.x & 63;
#pragma unroll
  for (int rr = 0; rr < 2; ++rr) {
    int r = r0 + w*2 + rr;
    float4 v = *(const float4*)&u[(size_t)r*HDIM + lane*4];
    float s = v.x+v.y+v.z+v.w;
    float sq = v.x*v.x + v.y*v.y + v.z*v.z + v.w*v.w;
    s = wave_sum64(s);
    sq = wave_sum64(sq);
    float mu = rdlane(s, 63) * (1.f/256.f);
    float ms = rdlane(sq, 63) * (1.f/256.f);
    float rstd = rsqrtf(ms - mu*mu + 1e-5f);
    float4 gg = *(const float4*)&g[lane*4];
    float4 bb = *(const float4*)&b[lane*4];
    float o[4];
    o[0] = (v.x-mu)*rstd*gg.x + bb.x;
    o[1] = (v.y-mu)*rstd*gg.y + bb.y;
    o[2] = (v.z-mu)*rstd*gg.z + bb.z;
    o[3] = (v.w-mu)*rstd*gg.w + bb.w;
    unsigned short sh[4], sl[4];
#pragma unroll
    for (int q = 0; q < 4; ++q) {
      sh[q] = f2bf(o[q]); sl[q] = f2bf(o[q] - bf2f(sh[q]));
    }
    size_t ob = (size_t)r*HDIM + lane*4;
    *(unsigned long long*)&unh[ob] = pk4(sh[0],sh[1],sh[2],sh[3]);
    *(unsigned long long*)&unl[ob] = pk4(sl[0],sl[1],sl[2],sl[3]);
  }
}

// ---------------- head: un @ Wh (3-term split MFMA)
__global__ __launch_bounds__(256) void head_mfma(
    const unsigned short* __restrict__ unh, const unsigned short* __restrict__ unl,
    const unsigned short* __restrict__ whh, const unsigned short* __restrict__ whl,
    const float* __restrict__ hb, float* __restrict__ out) {
  const int bx = blockIdx.x, by = blockIdx.y;
  const int tid = threadIdx.x, w = tid >> 6, l = tid & 63;
  facc4 acc[4];
#pragma unroll
  for (int nf = 0; nf < 4; ++nf) acc[nf] = (facc4){0.f,0.f,0.f,0.f};
  const int m0 = bx*64 + 16*w;
#pragma unroll
  for (int k0 = 0; k0 < HDIM; k0 += 32) {
    int ko = k0 + (l>>4)*8;
    size_t aaddr = (size_t)(m0 + (l&15))*HDIM + ko;
    bfrag8 ah = *(const bfrag8*)&unh[aaddr];
    bfrag8 al = *(const bfrag8*)&unl[aaddr];
#pragma unroll
    for (int nf = 0; nf < 4; ++nf) {
      int nrow = by*64 + 16*nf + (l&15);
      size_t baddr = (size_t)nrow*HDIM + ko;
      bfrag8 bh = *(const bfrag8*)&whh[baddr];
      bfrag8 bl = *(const bfrag8*)&whl[baddr];
      acc[nf] = __builtin_amdgcn_mfma_f32_16x16x32_bf16(ah, bh, acc[nf], 0,0,0);
      acc[nf] = __builtin_amdgcn_mfma_f32_16x16x32_bf16(al, bh, acc[nf], 0,0,0);
      acc[nf] = __builtin_amdgcn_mfma_f32_16x16x32_bf16(ah, bl, acc[nf], 0,0,0);
    }
  }
#pragma unroll
  for (int nf = 0; nf < 4; ++nf) {
    int c = by*64 + 16*nf + (l&15);
    if (c < OUTC) {
#pragma unroll
      for (int r = 0; r < 4; ++r) {
        int row = bx*64 + 16*w + 4*(l>>4) + r;
        out[(size_t)row*OUTC + c] = acc[nf][r] + hb[c];
      }
    }
  }
}

// ---------------- weight prep: transpose + split
__global__ void prep_wglu(const float* __restrict__ w,
    unsigned short* __restrict__ oh, unsigned short* __restrict__ ol) {
  __shared__ float t[32][33];
  int d = blockIdx.z, k0 = blockIdx.y*32, n0 = blockIdx.x*32;
  int tx = threadIdx.x, ty = threadIdx.y;
#pragma unroll
  for (int i = 0; i < 32; i += 8)
    t[ty+i][tx] = w[((size_t)(d*HDIM + k0+ty+i))*512 + n0+tx];
  __syncthreads();
#pragma unroll
  for (int i = 0; i < 32; i += 8) {
    float v = t[tx][ty+i];
    size_t o = ((size_t)(d*512 + n0+ty+i))*HDIM + k0+tx;
    unsigned short hh = f2bf(v);
    oh[o] = hh; ol[o] = f2bf(v - bf2f(hh));
  }
}

__global__ void prep_whead(const float* __restrict__ w,
    unsigned short* __restrict__ oh, unsigned short* __restrict__ ol) {
  __shared__ float t[32][33];
  int k0 = blockIdx.y*32, n0 = blockIdx.x*32;
  int tx = threadIdx.x, ty = threadIdx.y;
#pragma unroll
  for (int i = 0; i < 32; i += 8)
    t[ty+i][tx] = (n0+tx < OUTC) ? w[(size_t)(k0+ty+i)*OUTC + n0+tx] : 0.f;
  __syncthreads();
#pragma unroll
  for (int i = 0; i < 32; i += 8) {
    float v = t[tx][ty+i];
    size_t o = (size_t)(n0+ty+i)*HDIM + k0+tx;
    unsigned short hh = f2bf(v);
    oh[o] = hh; ol[o] = f2bf(v - bf2f(hh));
  }
}

extern "C" void kernel_launch(void* const* d_in, const int* in_sizes, int n_in,
                              void* d_out, int out_size, void* d_ws, size_t ws_size,
                              hipStream_t stream) {
  const float* x       = (const float*)d_in[0];
  const float* proj_w  = (const float*)d_in[1];
  const float* proj_b  = (const float*)d_in[2];
  const float* log_dt  = (const float*)d_in[3];
  const float* lAr     = (const float*)d_in[4];
  const float* Aim     = (const float*)d_in[5];
  const float* Cre     = (const float*)d_in[6];
  const float* Cim     = (const float*)d_in[7];
  const float* Dp      = (const float*)d_in[8];
  const float* out_w   = (const float*)d_in[9];
  const float* out_b   = (const float*)d_in[10];
  const float* ln_g    = (const float*)d_in[11];
  const float* ln_b    = (const float*)d_in[12];
  const float* head_w  = (const float*)d_in[13];
  const float* head_b  = (const float*)d_in[14];
  float* outp = (float*)d_out;

  // workspace budget check: bail loudly (poisoned output) rather than corrupt memory
  size_t need = (size_t)NROWS*HDIM*4*2          // u, zt
              + (size_t)NROWS*HDIM*2*4          // uth, utl, zh, zl
              + (size_t)10*M1*2                 // mats
              + (size_t)4*512*HDIM*2*2          // wgh, wgl
              + (size_t)HDIM*HDIM*2*2           // whh, whl
              + (size_t)4*HN*4;                 // coef
  if (ws_size < need) return;

  char* p = (char*)d_ws;
  float* u    = (float*)p;            p += (size_t)NROWS*HDIM*4;
  float* zt   = (float*)p;            p += (size_t)NROWS*HDIM*4;
  unsigned short* uth = (unsigned short*)p; p += (size_t)NROWS*HDIM*2;
  unsigned short* utl = (unsigned short*)p; p += (size_t)NROWS*HDIM*2;
  unsigned short* zh  = (unsigned short*)p; p += (size_t)NROWS*HDIM*2;
  unsigned short* zl  = (unsigned short*)p; p += (size_t)NROWS*HDIM*2;
  unsigned short* mats= (unsigned short*)p; p += (size_t)10*M1*2;
  unsigned short* wgh = (unsigned short*)p; p += (size_t)4*512*HDIM*2;
  unsigned short* wgl = (unsigned short*)p; p += (size_t)4*512*HDIM*2;
  unsigned short* whh = (unsigned short*)p; p += (size_t)HDIM*HDIM*2;
  unsigned short* whl = (unsigned short*)p; p += (size_t)HDIM*HDIM*2;
  float* coef = (float*)p;            p += (size_t)4*HN*4;
  unsigned short* unh = uth;  // reuse after last layer
  unsigned short* unl = utl;

  prep_wglu<<<dim3(16, 8, 4), dim3(32,8), 0, stream>>>(out_w, wgh, wgl);
  prep_whead<<<dim3(8, 8), dim3(32,8), 0, stream>>>(head_w, whh, whl);
  proj_kernel<<<NROWS/8, 256, 0, stream>>>(x, proj_w, proj_b, u, uth, utl);

  for (int d = 0; d < NDEPTH; ++d) {
    build_mats<<<HDIM, 256, 0, stream>>>(
        log_dt + d*HDIM, lAr + (size_t)d*HN, Aim + (size_t)d*HN,
        Cre + (size_t)d*HN, Cim + (size_t)d*HN, Dp + d*HDIM, mats, coef);
    scan_gemm<<<dim3(HDIM, NBATCH/2), 256, 0, stream>>>(uth, utl, mats, coef, zt);
    tsplit_kernel<<<dim3(LSEQ/32, HDIM/32, NBATCH), dim3(32,8), 0, stream>>>(zt, zh, zl);
    glu_mfma<<<dim3(NROWS/64, 4), 256, 0, stream>>>(
        zh, zl, wgh + (size_t)d*512*HDIM, wgl + (size_t)d*512*HDIM,
        out_b + d*512, u, uth, utl);
  }

  ln_kernel<<<NROWS/8, 256, 0, stream>>>(u, ln_g, ln_b, unh, unl);
  head_mfma<<<dim3(NROWS/64, 4), 256, 0, stream>>>(unh, unl, whh, whl, head_b, outp);
}

// Round 7
// 319.979 us; speedup vs baseline: 1.7253x; 1.7253x over previous
//
#include <hip/hip_runtime.h>
#include <math.h>

#define HDIM 256
#define NSTATE 64
#define NDEPTH 4
#define LSEQ 2048
#define NBATCH 8
#define NROWS (NBATCH*LSEQ)   // 16384
#define HN (HDIM*NSTATE)      // 16384
#define INDIM 51
#define OUTC 204
#define M1 (256*4096)         // shorts per variant (256 h x 64x64)
#define GPAD 40               // padded k-stride (shorts) for GEMM tiles

typedef short bfrag8 __attribute__((ext_vector_type(8)));
typedef float facc4 __attribute__((ext_vector_type(4)));

// ---------------- helpers ----------------
template<int CTRL>
__device__ __forceinline__ float dpp_add(float x) {
  int y = __builtin_amdgcn_update_dpp(0, __float_as_int(x), CTRL, 0xf, 0xf, true);
  return x + __int_as_float(y);
}
__device__ __forceinline__ float wave_sum64(float x) {
  x = dpp_add<0x111>(x);
  x = dpp_add<0x112>(x);
  x = dpp_add<0x114>(x);
  x = dpp_add<0x118>(x);
  x = dpp_add<0x142>(x);
  x = dpp_add<0x143>(x);
  return x;   // total in lane 63
}
__device__ __forceinline__ float rdlane(float v, int lane) {
  return __int_as_float(__builtin_amdgcn_readlane(__float_as_int(v), lane));
}
__device__ __forceinline__ float gelu_tanh(float x) {
  float x3 = x*x*x;
  return 0.5f*x*(1.f + tanhf(0.7978845608028654f*(x + 0.044715f*x3)));
}
__device__ __forceinline__ unsigned short f2bf(float x) {
  unsigned u = __float_as_uint(x);
  unsigned r = (u + 0x7FFFu + ((u >> 16) & 1u)) >> 16;
  return (unsigned short)r;
}
__device__ __forceinline__ float bf2f(unsigned short h) {
  return __uint_as_float(((unsigned)h) << 16);
}
__device__ __forceinline__ bfrag8 mk8(unsigned a, unsigned b, unsigned c, unsigned d) {
  union { unsigned u[4]; bfrag8 f; } U;
  U.u[0]=a; U.u[1]=b; U.u[2]=c; U.u[3]=d; return U.f;
}
__device__ __forceinline__ unsigned long long pk4(unsigned short a,unsigned short b,
                                                  unsigned short c,unsigned short d){
  return (unsigned long long)a | ((unsigned long long)b<<16) |
         ((unsigned long long)c<<32) | ((unsigned long long)d<<48);
}

// ---------------- input projection: x[16384,51] @ w[51,256] + b -> u fp32 + uth/utl splits
__global__ __launch_bounds__(256) void proj_kernel(
    const float* __restrict__ x, const float* __restrict__ w,
    const float* __restrict__ bias, float* __restrict__ u,
    unsigned short* __restrict__ uth, unsigned short* __restrict__ utl) {
  __shared__ float xs[8][52];
  const int r0 = blockIdx.x * 8;
  const int tid = threadIdx.x;
  for (int idx = tid; idx < 8*INDIM; idx += 256) {
    int rr = idx / INDIM, k = idx % INDIM;
    xs[rr][k] = x[(size_t)(r0+rr)*INDIM + k];
  }
  __syncthreads();
  const int hcol = tid;
  float acc[8];
  const float bb = bias[hcol];
#pragma unroll
  for (int rr = 0; rr < 8; ++rr) acc[rr] = bb;
#pragma unroll
  for (int k = 0; k < 48; k += 4) {
    float w0 = w[(k+0)*HDIM + hcol];
    float w1 = w[(k+1)*HDIM + hcol];
    float w2 = w[(k+2)*HDIM + hcol];
    float w3 = w[(k+3)*HDIM + hcol];
#pragma unroll
    for (int rr = 0; rr < 8; ++rr) {
      float4 xv = *(const float4*)&xs[rr][k];
      acc[rr] = fmaf(xv.x, w0, acc[rr]);
      acc[rr] = fmaf(xv.y, w1, acc[rr]);
      acc[rr] = fmaf(xv.z, w2, acc[rr]);
      acc[rr] = fmaf(xv.w, w3, acc[rr]);
    }
  }
#pragma unroll
  for (int k = 48; k < INDIM; ++k) {
    float wk = w[k*HDIM + hcol];
#pragma unroll
    for (int rr = 0; rr < 8; ++rr) acc[rr] = fmaf(xs[rr][k], wk, acc[rr]);
  }
  unsigned short sh[8], sl[8];
#pragma unroll
  for (int rr = 0; rr < 8; ++rr) {
    u[(size_t)(r0+rr)*HDIM + hcol] = acc[rr];
    unsigned short hh = f2bf(acc[rr]);
    sh[rr] = hh; sl[rr] = f2bf(acc[rr] - bf2f(hh));
  }
  const int b = r0 >> 11, lw = r0 & 2047;
  size_t ob = ((size_t)(b*HDIM + hcol))*LSEQ + lw;
  *(unsigned long long*)&uth[ob]   = pk4(sh[0],sh[1],sh[2],sh[3]);
  *(unsigned long long*)&uth[ob+4] = pk4(sh[4],sh[5],sh[6],sh[7]);
  *(unsigned long long*)&utl[ob]   = pk4(sl[0],sl[1],sl[2],sl[3]);
  *(unsigned long long*)&utl[ob+4] = pk4(sl[4],sl[5],sl[6],sl[7]);
}

// ---------------- build per-layer matrices into fragment-tiled global buffers
// mats layout (shorts): E2 v=0..3 at v*M1 ; Epow v=0..3 at (4+v)*M1 ; T v=0..1 at (8+v)*M1
// tile addr within a 64x64 matrix: ((row>>4)*2 + (k>>5))*512 + (row&15)*32 + (k&31)
__device__ __forceinline__ void copy_mats4(const unsigned short (*BB)[64][68],
    unsigned short* dst, int h, int tid) {
#pragma unroll
  for (int v = 0; v < 4; ++v) {
    unsigned int* dv = (unsigned int*)(dst + (size_t)v*M1 + (size_t)h*4096);
    for (int uu = tid; uu < 2048; uu += 256) {
      int toff = uu*2;
      int tile = toff >> 9, win = toff & 511;
      int row = (tile>>1)*16 + (win>>5);
      int k   = (tile&1)*32 + (win&31);
      dv[uu] = *(const unsigned int*)&BB[v][row][k];
    }
  }
}

__global__ __launch_bounds__(256) void build_mats(
    const float* __restrict__ log_dt, const float* __restrict__ lAr,
    const float* __restrict__ Aim, const float* __restrict__ Cre,
    const float* __restrict__ Cim, const float* __restrict__ Dv,
    unsigned short* __restrict__ mats, float* __restrict__ coef) {
  __shared__ unsigned short BB[4][64][68];
  __shared__ float kvs[64];
  const int h = blockIdx.x;
  const int tid = threadIdx.x;
  const int w = tid >> 6, l = tid & 63;
  const int i0 = h*64 + l;
  float dt = expf(log_dt[h]);
  float Ar = -expf(lAr[i0]);
  float Ai = Aim[i0];
  float e  = expf(Ar*dt);
  float ar = e * cosf(Ai*dt), ai = e * sinf(Ai*dt);
  float inv = 1.f/(Ar*Ar + Ai*Ai);
  float nre = ar - 1.f, nim = ai;
  float qre = (nre*Ar + nim*Ai)*inv;
  float qim = (nim*Ar - nre*Ai)*inv;
  float cre0 = Cre[i0], cim0 = Cim[i0];
  float cr = 2.f*(cre0*qre - cim0*qim);
  float ci = 2.f*(cre0*qim + cim0*qre);
  float Dh = Dv[h];
  // powers of a
  float a2r = ar*ar - ai*ai,     a2i = 2.f*ar*ai;
  float a4r = a2r*a2r - a2i*a2i, a4i = 2.f*a2r*a2i;
  float a8r = a4r*a4r - a4i*a4i, a8i = 2.f*a4r*a4i;
  float a16r= a8r*a8r - a8i*a8i, a16i= 2.f*a8r*a8i;
  float a32r= a16r*a16r - a16i*a16i, a32i = 2.f*a16r*a16i;
  float a48r= a32r*a16r - a32i*a16i, a48i = a32r*a16i + a32i*a16r;
  float a64r= a32r*a32r - a32i*a32i, a64i = 2.f*a32r*a32i;
  if (w == 0) {
    coef[0*HN + i0] = a64r; coef[1*HN + i0] = a64i;
    coef[2*HN + i0] = cr;   coef[3*HN + i0] = ci;
  }
  // kv: wave w handles m in [16w,16w+16)
  {
    float br, bi2;
    if      (w == 0) { br = 1.f;  bi2 = 0.f;  }
    else if (w == 1) { br = a16r; bi2 = a16i; }
    else if (w == 2) { br = a32r; bi2 = a32i; }
    else             { br = a48r; bi2 = a48i; }
    float tr = cr*br - ci*bi2, ti = cr*bi2 + ci*br;
#pragma unroll
    for (int mm = 0; mm < 16; ++mm) {
      float s = wave_sum64(tr);
      if (l == 63) kvs[16*w + mm] = s;
      float nr = tr*ar - ti*ai, ni = tr*ai + ti*ar;
      tr = nr; ti = ni;
    }
  }
  // E2[n=l][j] = a^{63-j}; wave w covers j in [16w,16w+16), descending
  {
    float pr, pi;
    if      (w == 3) { pr = 1.f;  pi = 0.f;  }
    else if (w == 2) { pr = a16r; pi = a16i; }
    else if (w == 1) { pr = a32r; pi = a32i; }
    else             { pr = a48r; pi = a48i; }
    for (int j = 16*w+15; j >= 16*w; --j) {
      unsigned short hh = f2bf(pr);
      BB[0][l][j] = hh; BB[1][l][j] = f2bf(pr - bf2f(hh));
      hh = f2bf(pi);
      BB[2][l][j] = hh; BB[3][l][j] = f2bf(pi - bf2f(hh));
      float nr = pr*ar - pi*ai, ni = pr*ai + pi*ar;
      pr = nr; pi = ni;
    }
  }
  __syncthreads();
  copy_mats4(BB, mats, h, tid);
  __syncthreads();
  // Epow[t][n=l] = a^{t+1}, imaginary part negated
  {
    float pr, pi;
    if      (w == 0) { pr = ar; pi = ai; }
    else if (w == 1) { pr = a16r*ar - a16i*ai; pi = a16r*ai + a16i*ar; }
    else if (w == 2) { pr = a32r*ar - a32i*ai; pi = a32r*ai + a32i*ar; }
    else             { pr = a48r*ar - a48i*ai; pi = a48r*ai + a48i*ar; }
    for (int t = 16*w; t < 16*w+16; ++t) {
      unsigned short hh = f2bf(pr);
      BB[0][t][l] = hh; BB[1][t][l] = f2bf(pr - bf2f(hh));
      float nv = -pi;
      hh = f2bf(nv);
      BB[2][t][l] = hh; BB[3][t][l] = f2bf(nv - bf2f(hh));
      float nr = pr*ar - pi*ai, ni = pr*ai + pi*ar;
      pr = nr; pi = ni;
    }
  }
  __syncthreads();
  copy_mats4(BB, mats + (size_t)4*M1, h, tid);
  // T[t][j] = k_{t-j} (t>=j) + Dh on diagonal, written straight to global (tiled order)
  for (int idx = tid; idx < 4096; idx += 256) {
    int tile = idx >> 9, win = idx & 511;
    int row = (tile>>1)*16 + (win>>5);
    int jj  = (tile&1)*32 + (win&31);
    int dm = row - jj;
    float v = 0.f;
    if (dm >= 0) v = kvs[dm] + (dm == 0 ? Dh : 0.f);
    unsigned short hh = f2bf(v);
    mats[(size_t)8*M1 + (size_t)h*4096 + idx] = hh;
    mats[(size_t)9*M1 + (size_t)h*4096 + idx] = f2bf(v - bf2f(hh));
  }
}

// ---------------- lean MFMA scan: block = (h, batch-pair), 64 cols = 32 chunks x 2 batches
// u tile staged in LDS once (coalesced), all A-frags from LDS. Outputs z splits [b,h,l].
__device__ __forceinline__ void gemm_conv(facc4 (&acc)[4],
    const unsigned short (*UU)[64][72],
    const unsigned short* __restrict__ tmat, int w, int l) {
#pragma unroll
  for (int kb = 0; kb < 2; ++kb) {
    int bo = (w*2+kb)*512 + (l&15)*32 + (l>>4)*8;
    bfrag8 bth = *(const bfrag8*)&tmat[bo];
    bfrag8 btl = *(const bfrag8*)&tmat[M1 + bo];
    int koff = kb*32 + (l>>4)*8;
#pragma unroll
    for (int mt = 0; mt < 4; ++mt) {
      int arow = 16*mt + (l&15);
      bfrag8 ah = *(const bfrag8*)&UU[0][arow][koff];
      bfrag8 al = *(const bfrag8*)&UU[1][arow][koff];
      acc[mt] = __builtin_amdgcn_mfma_f32_16x16x32_bf16(ah, bth, acc[mt], 0,0,0);
      acc[mt] = __builtin_amdgcn_mfma_f32_16x16x32_bf16(al, bth, acc[mt], 0,0,0);
      acc[mt] = __builtin_amdgcn_mfma_f32_16x16x32_bf16(ah, btl, acc[mt], 0,0,0);
    }
  }
}

__global__ __launch_bounds__(256) void scan_gemm(
    const unsigned short* __restrict__ uth, const unsigned short* __restrict__ utl,
    const unsigned short* __restrict__ mats, const float* __restrict__ coef,
    unsigned short* __restrict__ zth, unsigned short* __restrict__ ztl) {
  __shared__ unsigned int SM[2][64][68];                  // f32 s_end -> packed bf16-split w
  __shared__ __align__(16) unsigned short UU[2][64][72];  // u splits [col][j]
  const int h = blockIdx.x, bp = blockIdx.y;
  const int tid = threadIdx.x, w = tid >> 6, l = tid & 63;

  // ---- stage u tile: 2 splits x 2 batches x 2048 l, coalesced 16B chunks
#pragma unroll
  for (int p = 0; p < 4; ++p) {
    int ch = tid + p*256;           // 1024 chunks of 8 shorts
    int sp = ch >> 9;
    int bi = (ch >> 8) & 1;
    int loff = (ch & 255) * 8;
    const unsigned short* src = sp ? utl : uth;
    uint4 v = *(const uint4*)&src[((size_t)((2*bp+bi)*HDIM + h))*LSEQ + loff];
    *(uint4*)&UU[sp][bi*32 + (loff>>6)][loff & 63] = v;
  }
  __syncthreads();

  // ---- GEMM-A: s_end[col][n]
  {
    facc4 are[4], aim[4];
#pragma unroll
    for (int mt = 0; mt < 4; ++mt) { are[mt] = (facc4){0.f,0.f,0.f,0.f}; aim[mt] = (facc4){0.f,0.f,0.f,0.f}; }
    const unsigned short* e2 = mats + (size_t)h*4096;
#pragma unroll
    for (int kb = 0; kb < 2; ++kb) {
      int bo = (w*2+kb)*512 + (l&15)*32 + (l>>4)*8;
      bfrag8 brh = *(const bfrag8*)&e2[(size_t)0*M1 + bo];
      bfrag8 brl = *(const bfrag8*)&e2[(size_t)1*M1 + bo];
      bfrag8 bih = *(const bfrag8*)&e2[(size_t)2*M1 + bo];
      bfrag8 bil = *(const bfrag8*)&e2[(size_t)3*M1 + bo];
      int koff = kb*32 + (l>>4)*8;
#pragma unroll
      for (int mt = 0; mt < 4; ++mt) {
        int arow = 16*mt + (l&15);
        bfrag8 ah = *(const bfrag8*)&UU[0][arow][koff];
        bfrag8 al = *(const bfrag8*)&UU[1][arow][koff];
        are[mt] = __builtin_amdgcn_mfma_f32_16x16x32_bf16(ah, brh, are[mt], 0,0,0);
        are[mt] = __builtin_amdgcn_mfma_f32_16x16x32_bf16(al, brh, are[mt], 0,0,0);
        are[mt] = __builtin_amdgcn_mfma_f32_16x16x32_bf16(ah, brl, are[mt], 0,0,0);
        aim[mt] = __builtin_amdgcn_mfma_f32_16x16x32_bf16(ah, bih, aim[mt], 0,0,0);
        aim[mt] = __builtin_amdgcn_mfma_f32_16x16x32_bf16(al, bih, aim[mt], 0,0,0);
        aim[mt] = __builtin_amdgcn_mfma_f32_16x16x32_bf16(ah, bil, aim[mt], 0,0,0);
      }
    }
#pragma unroll
    for (int mt = 0; mt < 4; ++mt)
#pragma unroll
      for (int r = 0; r < 4; ++r) {
        int colg = 16*mt + 4*(l>>4) + r;
        int ng   = 16*w + (l&15);
        ((float*)&SM[0][0][0])[colg*68 + ng] = are[mt][r];
        ((float*)&SM[1][0][0])[colg*68 + ng] = aim[mt][r];
      }
  }
  __syncthreads();

  facc4 acc[4];
#pragma unroll
  for (int mt = 0; mt < 4; ++mt) acc[mt] = (facc4){0.f,0.f,0.f,0.f};
  const unsigned short* tmat = mats + (size_t)8*M1 + (size_t)h*4096;

  if (w < 2) {
    // serial chunk-state combine for batch w; packs w-splits in place
    const int i0 = h*64 + l;
    float a64r = coef[0*HN+i0], a64i = coef[1*HN+i0];
    float cr = coef[2*HN+i0],   ci = coef[3*HN+i0];
    float rr = 0.f, ri = 0.f;
    float* pre = (float*)&SM[0][0][0];
    float* pim = (float*)&SM[1][0][0];
    for (int c = 0; c < 32; ++c) {
      int off = (w*32 + c)*68 + l;
      float tre = pre[off], tim = pim[off];
      float wre = cr*rr - ci*ri;
      float wim = cr*ri + ci*rr;
      unsigned short hh = f2bf(wre);
      unsigned short lo = f2bf(wre - bf2f(hh));
      ((unsigned int*)pre)[off] = (unsigned)hh | ((unsigned)lo << 16);
      hh = f2bf(wim); lo = f2bf(wim - bf2f(hh));
      ((unsigned int*)pim)[off] = (unsigned)hh | ((unsigned)lo << 16);
      float nr = a64r*rr - a64i*ri + tre;
      float ni = a64r*ri + a64i*rr + tim;
      rr = nr; ri = ni;
    }
  } else {
    gemm_conv(acc, UU, tmat, w, l);   // waves 2,3 overlap the combine
  }
  __syncthreads();
  if (w < 2) gemm_conv(acc, UU, tmat, w, l);

  // ---- GEMM-B: correction, A = packed w from LDS, B = Epow from global
  {
    const unsigned short* ep = mats + (size_t)4*M1 + (size_t)h*4096;
#pragma unroll
    for (int kb = 0; kb < 2; ++kb) {
      int bo = (w*2+kb)*512 + (l&15)*32 + (l>>4)*8;
      bfrag8 erh = *(const bfrag8*)&ep[(size_t)0*M1 + bo];
      bfrag8 erl = *(const bfrag8*)&ep[(size_t)1*M1 + bo];
      bfrag8 eih = *(const bfrag8*)&ep[(size_t)2*M1 + bo];
      bfrag8 eil = *(const bfrag8*)&ep[(size_t)3*M1 + bo];
#pragma unroll
      for (int mt = 0; mt < 4; ++mt) {
        int arow = 16*mt + (l&15);
        int ko = kb*32 + (l>>4)*8;
        const unsigned int* p0 = &SM[0][0][0] + arow*68 + ko;
        const unsigned int* p1 = &SM[1][0][0] + arow*68 + ko;
        uint4 q0 = *(const uint4*)p0;
        uint4 q1 = *(const uint4*)(p0 + 4);
        uint4 s0 = *(const uint4*)p1;
        uint4 s1 = *(const uint4*)(p1 + 4);
        bfrag8 wrh = mk8((q0.x&0xffffu)|(q0.y<<16), (q0.z&0xffffu)|(q0.w<<16),
                         (q1.x&0xffffu)|(q1.y<<16), (q1.z&0xffffu)|(q1.w<<16));
        bfrag8 wrl = mk8((q0.x>>16)|(q0.y&0xffff0000u), (q0.z>>16)|(q0.w&0xffff0000u),
                         (q1.x>>16)|(q1.y&0xffff0000u), (q1.z>>16)|(q1.w&0xffff0000u));
        bfrag8 wih = mk8((s0.x&0xffffu)|(s0.y<<16), (s0.z&0xffffu)|(s0.w<<16),
                         (s1.x&0xffffu)|(s1.y<<16), (s1.z&0xffffu)|(s1.w<<16));
        bfrag8 wil = mk8((s0.x>>16)|(s0.y&0xffff0000u), (s0.z>>16)|(s0.w&0xffff0000u),
                         (s1.x>>16)|(s1.y&0xffff0000u), (s1.z>>16)|(s1.w&0xffff0000u));
        acc[mt] = __builtin_amdgcn_mfma_f32_16x16x32_bf16(wrh, erh, acc[mt], 0,0,0);
        acc[mt] = __builtin_amdgcn_mfma_f32_16x16x32_bf16(wrl, erh, acc[mt], 0,0,0);
        acc[mt] = __builtin_amdgcn_mfma_f32_16x16x32_bf16(wrh, erl, acc[mt], 0,0,0);
        acc[mt] = __builtin_amdgcn_mfma_f32_16x16x32_bf16(wih, eih, acc[mt], 0,0,0);
        acc[mt] = __builtin_amdgcn_mfma_f32_16x16x32_bf16(wil, eih, acc[mt], 0,0,0);
        acc[mt] = __builtin_amdgcn_mfma_f32_16x16x32_bf16(wih, eil, acc[mt], 0,0,0);
      }
    }
  }
  // ---- epilogue: gelu -> z splits in [b,h,l]
  const int tg = 16*w + (l&15);
#pragma unroll
  for (int mt = 0; mt < 4; ++mt)
#pragma unroll
    for (int r = 0; r < 4; ++r) {
      int colg = 16*mt + 4*(l>>4) + r;
      float gv = gelu_tanh(acc[mt][r]);
      size_t zo = ((size_t)((2*bp + (colg>>5))*HDIM + h))*LSEQ + (size_t)(colg&31)*64 + tg;
      unsigned short hh = f2bf(gv);
      zth[zo] = hh;
      ztl[zo] = f2bf(gv - bf2f(hh));
    }
}

// ---------------- z splits [b,h,l] -> [b,l,h]
__global__ void tsplit2(const unsigned short* __restrict__ ih, const unsigned short* __restrict__ il,
                        unsigned short* __restrict__ oh, unsigned short* __restrict__ ol) {
  __shared__ unsigned short th[32][34], tl2[32][34];
  int b = blockIdx.z, l0 = blockIdx.x*32, h0 = blockIdx.y*32;
  int tx = threadIdx.x, ty = threadIdx.y;   // (32,8)
#pragma unroll
  for (int i = 0; i < 32; i += 8) {
    size_t ga = ((size_t)(b*HDIM + h0+ty+i))*LSEQ + l0+tx;
    th[ty+i][tx] = ih[ga];
    tl2[ty+i][tx] = il[ga];
  }
  __syncthreads();
#pragma unroll
  for (int i = 0; i < 32; i += 8) {
    size_t o = ((size_t)(b*LSEQ + l0+ty+i))*HDIM + h0+tx;
    oh[o] = th[tx][ty+i];
    ol[o] = tl2[tx][ty+i];
  }
}

// ---------------- GLU: LDS-staged split-bf16 MFMA GEMM, tile 128l x (64a+64g)c
__global__ __launch_bounds__(256) void glu_tile(
    const unsigned short* __restrict__ zh, const unsigned short* __restrict__ zl,
    const unsigned short* __restrict__ wgh, const unsigned short* __restrict__ wgl,
    const float* __restrict__ bias, float* __restrict__ u,
    unsigned short* __restrict__ uth, unsigned short* __restrict__ utl) {
  __shared__ __align__(16) unsigned short LB[4*128*GPAD];  // Ah Al Bh Bl; epilogue: TT f32[64][132]
  unsigned short* Ah = LB;
  unsigned short* Al = LB + 128*GPAD;
  unsigned short* Bh = LB + 2*128*GPAD;
  unsigned short* Bl = LB + 3*128*GPAD;
  const int bx = blockIdx.x, by = blockIdx.y;
  const int tid = threadIdx.x, w = tid >> 6, l = tid & 63;
  const int r0 = bx*128, c0 = by*64;
  facc4 acc[2][4][2];
#pragma unroll
  for (int mt=0;mt<2;++mt)
#pragma unroll
    for (int nf=0;nf<4;++nf)
#pragma unroll
      for (int ag=0;ag<2;++ag) acc[mt][nf][ag] = (facc4){0.f,0.f,0.f,0.f};

  for (int k0 = 0; k0 < HDIM; k0 += 32) {
    __syncthreads();
#pragma unroll
    for (int p = 0; p < 2; ++p) {
      int ch = tid + p*256;          // 512 chunks
      int m = ch >> 2, c8 = (ch & 3) * 8;
      size_t ga = (size_t)(r0+m)*HDIM + k0 + c8;
      *(uint4*)&Ah[m*GPAD + c8] = *(const uint4*)&zh[ga];
      *(uint4*)&Al[m*GPAD + c8] = *(const uint4*)&zl[ga];
      int grow = c0 + (m & 63) + ((m & 64) ? 256 : 0);
      size_t gb = (size_t)grow*HDIM + k0 + c8;
      *(uint4*)&Bh[m*GPAD + c8] = *(const uint4*)&wgh[gb];
      *(uint4*)&Bl[m*GPAD + c8] = *(const uint4*)&wgl[gb];
    }
    __syncthreads();
    const int koff = (l>>4)*8;
    bfrag8 afh[2], afl[2];
#pragma unroll
    for (int mt=0;mt<2;++mt) {
      int row = w*32 + 16*mt + (l&15);
      afh[mt] = *(const bfrag8*)&Ah[row*GPAD + koff];
      afl[mt] = *(const bfrag8*)&Al[row*GPAD + koff];
    }
#pragma unroll
    for (int ag=0; ag<2; ++ag)
#pragma unroll
      for (int nf=0; nf<4; ++nf) {
        int brow = ag*64 + 16*nf + (l&15);
        bfrag8 bh = *(const bfrag8*)&Bh[brow*GPAD + koff];
        bfrag8 bl = *(const bfrag8*)&Bl[brow*GPAD + koff];
#pragma unroll
        for (int mt=0;mt<2;++mt) {
          acc[mt][nf][ag] = __builtin_amdgcn_mfma_f32_16x16x32_bf16(afh[mt], bh, acc[mt][nf][ag], 0,0,0);
          acc[mt][nf][ag] = __builtin_amdgcn_mfma_f32_16x16x32_bf16(afl[mt], bh, acc[mt][nf][ag], 0,0,0);
          acc[mt][nf][ag] = __builtin_amdgcn_mfma_f32_16x16x32_bf16(afh[mt], bl, acc[mt][nf][ag], 0,0,0);
        }
      }
  }
  __syncthreads();
  float* TT = (float*)LB;   // [64][132]
  const int b = r0 >> 11, l0 = r0 & 2047;
#pragma unroll
  for (int mt=0;mt<2;++mt)
#pragma unroll
    for (int nf=0;nf<4;++nf)
#pragma unroll
      for (int r=0;r<4;++r) {
        int m = w*32 + 16*mt + 4*(l>>4) + r;
        int cc = 16*nf + (l&15);
        int c = c0 + cc;
        float av = acc[mt][nf][0][r] + bias[c];
        float gv = acc[mt][nf][1][r] + bias[256+c];
        float val = u[(size_t)(r0+m)*HDIM + c] + av * (1.f/(1.f + expf(-gv)));
        u[(size_t)(r0+m)*HDIM + c] = val;
        TT[cc*132 + m] = val;
      }
  __syncthreads();
  {
    int cc = tid >> 2, mq = (tid & 3)*32;
    size_t ob = ((size_t)(b*HDIM + c0+cc))*LSEQ + l0 + mq;
#pragma unroll
    for (int q4 = 0; q4 < 32; q4 += 4) {
      float4 v = *(const float4*)&TT[cc*132 + mq + q4];
      float vv[4] = {v.x,v.y,v.z,v.w};
      unsigned short sh[4], sl[4];
#pragma unroll
      for (int q=0;q<4;++q){ sh[q]=f2bf(vv[q]); sl[q]=f2bf(vv[q]-bf2f(sh[q])); }
      *(unsigned long long*)&uth[ob+q4] = pk4(sh[0],sh[1],sh[2],sh[3]);
      *(unsigned long long*)&utl[ob+q4] = pk4(sl[0],sl[1],sl[2],sl[3]);
    }
  }
}

// ---------------- LayerNorm -> split-bf16 un
__global__ __launch_bounds__(256) void ln_kernel(
    const float* __restrict__ u, const float* __restrict__ g,
    const float* __restrict__ b, unsigned short* __restrict__ unh,
    unsigned short* __restrict__ unl) {
  const int r0 = blockIdx.x * 8;
  const int w = threadIdx.x >> 6;
  const int lane = threadIdx.x & 63;
#pragma unroll
  for (int rr = 0; rr < 2; ++rr) {
    int r = r0 + w*2 + rr;
    float4 v = *(const float4*)&u[(size_t)r*HDIM + lane*4];
    float s = v.x+v.y+v.z+v.w;
    float sq = v.x*v.x + v.y*v.y + v.z*v.z + v.w*v.w;
    s = wave_sum64(s);
    sq = wave_sum64(sq);
    float mu = rdlane(s, 63) * (1.f/256.f);
    float ms = rdlane(sq, 63) * (1.f/256.f);
    float rstd = rsqrtf(ms - mu*mu + 1e-5f);
    float4 gg = *(const float4*)&g[lane*4];
    float4 bb = *(const float4*)&b[lane*4];
    float o[4];
    o[0] = (v.x-mu)*rstd*gg.x + bb.x;
    o[1] = (v.y-mu)*rstd*gg.y + bb.y;
    o[2] = (v.z-mu)*rstd*gg.z + bb.z;
    o[3] = (v.w-mu)*rstd*gg.w + bb.w;
    unsigned short sh[4], sl[4];
#pragma unroll
    for (int q = 0; q < 4; ++q) {
      sh[q] = f2bf(o[q]); sl[q] = f2bf(o[q] - bf2f(sh[q]));
    }
    size_t ob = (size_t)r*HDIM + lane*4;
    *(unsigned long long*)&unh[ob] = pk4(sh[0],sh[1],sh[2],sh[3]);
    *(unsigned long long*)&unl[ob] = pk4(sl[0],sl[1],sl[2],sl[3]);
  }
}

// ---------------- head: LDS-staged split-bf16 MFMA GEMM, tile 128r x 64c
__global__ __launch_bounds__(256) void head_tile(
    const unsigned short* __restrict__ unh, const unsigned short* __restrict__ unl,
    const unsigned short* __restrict__ whh, const unsigned short* __restrict__ whl,
    const float* __restrict__ hb, float* __restrict__ out) {
  __shared__ __align__(16) unsigned short LB[(2*128 + 2*64)*GPAD];
  unsigned short* Ah = LB;
  unsigned short* Al = LB + 128*GPAD;
  unsigned short* Bh = LB + 2*128*GPAD;
  unsigned short* Bl = LB + 2*128*GPAD + 64*GPAD;
  const int bx = blockIdx.x, by = blockIdx.y;
  const int tid = threadIdx.x, w = tid >> 6, l = tid & 63;
  const int r0 = bx*128, c0 = by*64;
  facc4 acc[2][4];
#pragma unroll
  for (int mt=0;mt<2;++mt)
#pragma unroll
    for (int nf=0;nf<4;++nf) acc[mt][nf] = (facc4){0.f,0.f,0.f,0.f};

  for (int k0 = 0; k0 < HDIM; k0 += 32) {
    __syncthreads();
#pragma unroll
    for (int p = 0; p < 2; ++p) {
      int ch = tid + p*256;
      int m = ch >> 2, c8 = (ch & 3) * 8;
      size_t ga = (size_t)(r0+m)*HDIM + k0 + c8;
      *(uint4*)&Ah[m*GPAD + c8] = *(const uint4*)&unh[ga];
      *(uint4*)&Al[m*GPAD + c8] = *(const uint4*)&unl[ga];
    }
    {
      int m = tid >> 2, c8 = (tid & 3) * 8;   // 256 chunks for 64 rows
      size_t gb = (size_t)(c0+m)*HDIM + k0 + c8;
      *(uint4*)&Bh[m*GPAD + c8] = *(const uint4*)&whh[gb];
      *(uint4*)&Bl[m*GPAD + c8] = *(const uint4*)&whl[gb];
    }
    __syncthreads();
    const int koff = (l>>4)*8;
    bfrag8 afh[2], afl[2];
#pragma unroll
    for (int mt=0;mt<2;++mt) {
      int row = w*32 + 16*mt + (l&15);
      afh[mt] = *(const bfrag8*)&Ah[row*GPAD + koff];
      afl[mt] = *(const bfrag8*)&Al[row*GPAD + koff];
    }
#pragma unroll
    for (int nf=0; nf<4; ++nf) {
      int brow = 16*nf + (l&15);
      bfrag8 bh = *(const bfrag8*)&Bh[brow*GPAD + koff];
      bfrag8 bl = *(const bfrag8*)&Bl[brow*GPAD + koff];
#pragma unroll
      for (int mt=0;mt<2;++mt) {
        acc[mt][nf] = __builtin_amdgcn_mfma_f32_16x16x32_bf16(afh[mt], bh, acc[mt][nf], 0,0,0);
        acc[mt][nf] = __builtin_amdgcn_mfma_f32_16x16x32_bf16(afl[mt], bh, acc[mt][nf], 0,0,0);
        acc[mt][nf] = __builtin_amdgcn_mfma_f32_16x16x32_bf16(afh[mt], bl, acc[mt][nf], 0,0,0);
      }
    }
  }
#pragma unroll
  for (int mt=0;mt<2;++mt)
#pragma unroll
    for (int nf=0;nf<4;++nf) {
      int c = c0 + 16*nf + (l&15);
      if (c < OUTC) {
#pragma unroll
        for (int r=0;r<4;++r) {
          int m = w*32 + 16*mt + 4*(l>>4) + r;
          out[(size_t)(r0+m)*OUTC + c] = acc[mt][nf][r] + hb[c];
        }
      }
    }
}

// ---------------- weight prep: transpose + split
__global__ void prep_wglu(const float* __restrict__ w,
    unsigned short* __restrict__ oh, unsigned short* __restrict__ ol) {
  __shared__ float t[32][33];
  int d = blockIdx.z, k0 = blockIdx.y*32, n0 = blockIdx.x*32;
  int tx = threadIdx.x, ty = threadIdx.y;
#pragma unroll
  for (int i = 0; i < 32; i += 8)
    t[ty+i][tx] = w[((size_t)(d*HDIM + k0+ty+i))*512 + n0+tx];
  __syncthreads();
#pragma unroll
  for (int i = 0; i < 32; i += 8) {
    float v = t[tx][ty+i];
    size_t o = ((size_t)(d*512 + n0+ty+i))*HDIM + k0+tx;
    unsigned short hh = f2bf(v);
    oh[o] = hh; ol[o] = f2bf(v - bf2f(hh));
  }
}

__global__ void prep_whead(const float* __restrict__ w,
    unsigned short* __restrict__ oh, unsigned short* __restrict__ ol) {
  __shared__ float t[32][33];
  int k0 = blockIdx.y*32, n0 = blockIdx.x*32;
  int tx = threadIdx.x, ty = threadIdx.y;
#pragma unroll
  for (int i = 0; i < 32; i += 8)
    t[ty+i][tx] = (n0+tx < OUTC) ? w[(size_t)(k0+ty+i)*OUTC + n0+tx] : 0.f;
  __syncthreads();
#pragma unroll
  for (int i = 0; i < 32; i += 8) {
    float v = t[tx][ty+i];
    size_t o = (size_t)(n0+ty+i)*HDIM + k0+tx;
    unsigned short hh = f2bf(v);
    oh[o] = hh; ol[o] = f2bf(v - bf2f(hh));
  }
}

extern "C" void kernel_launch(void* const* d_in, const int* in_sizes, int n_in,
                              void* d_out, int out_size, void* d_ws, size_t ws_size,
                              hipStream_t stream) {
  const float* x       = (const float*)d_in[0];
  const float* proj_w  = (const float*)d_in[1];
  const float* proj_b  = (const float*)d_in[2];
  const float* log_dt  = (const float*)d_in[3];
  const float* lAr     = (const float*)d_in[4];
  const float* Aim     = (const float*)d_in[5];
  const float* Cre     = (const float*)d_in[6];
  const float* Cim     = (const float*)d_in[7];
  const float* Dp      = (const float*)d_in[8];
  const float* out_w   = (const float*)d_in[9];
  const float* out_b   = (const float*)d_in[10];
  const float* ln_g    = (const float*)d_in[11];
  const float* ln_b    = (const float*)d_in[12];
  const float* head_w  = (const float*)d_in[13];
  const float* head_b  = (const float*)d_in[14];
  float* outp = (float*)d_out;

  size_t need = (size_t)NROWS*HDIM*4          // u fp32
              + (size_t)NROWS*HDIM*2*6        // uth, utl, zth, ztl, zh, zl
              + (size_t)10*M1*2               // mats
              + (size_t)4*512*HDIM*2*2        // wgh, wgl
              + (size_t)HDIM*HDIM*2*2         // whh, whl
              + (size_t)4*HN*4;               // coef
  if (ws_size < need) return;

  char* p = (char*)d_ws;
  float* u    = (float*)p;            p += (size_t)NROWS*HDIM*4;
  unsigned short* uth = (unsigned short*)p; p += (size_t)NROWS*HDIM*2;
  unsigned short* utl = (unsigned short*)p; p += (size_t)NROWS*HDIM*2;
  unsigned short* zth = (unsigned short*)p; p += (size_t)NROWS*HDIM*2;
  unsigned short* ztl = (unsigned short*)p; p += (size_t)NROWS*HDIM*2;
  unsigned short* zh  = (unsigned short*)p; p += (size_t)NROWS*HDIM*2;
  unsigned short* zl  = (unsigned short*)p; p += (size_t)NROWS*HDIM*2;
  unsigned short* mats= (unsigned short*)p; p += (size_t)10*M1*2;
  unsigned short* wgh = (unsigned short*)p; p += (size_t)4*512*HDIM*2;
  unsigned short* wgl = (unsigned short*)p; p += (size_t)4*512*HDIM*2;
  unsigned short* whh = (unsigned short*)p; p += (size_t)HDIM*HDIM*2;
  unsigned short* whl = (unsigned short*)p; p += (size_t)HDIM*HDIM*2;
  float* coef = (float*)p;            p += (size_t)4*HN*4;
  unsigned short* unh = uth;  // reuse after last layer
  unsigned short* unl = utl;

  prep_wglu<<<dim3(16, 8, 4), dim3(32,8), 0, stream>>>(out_w, wgh, wgl);
  prep_whead<<<dim3(8, 8), dim3(32,8), 0, stream>>>(head_w, whh, whl);
  proj_kernel<<<NROWS/8, 256, 0, stream>>>(x, proj_w, proj_b, u, uth, utl);

  for (int d = 0; d < NDEPTH; ++d) {
    build_mats<<<HDIM, 256, 0, stream>>>(
        log_dt + d*HDIM, lAr + (size_t)d*HN, Aim + (size_t)d*HN,
        Cre + (size_t)d*HN, Cim + (size_t)d*HN, Dp + d*HDIM, mats, coef);
    scan_gemm<<<dim3(HDIM, NBATCH/2), 256, 0, stream>>>(uth, utl, mats, coef, zth, ztl);
    tsplit2<<<dim3(LSEQ/32, HDIM/32, NBATCH), dim3(32,8), 0, stream>>>(zth, ztl, zh, zl);
    glu_tile<<<dim3(NROWS/128, 4), 256, 0, stream>>>(
        zh, zl, wgh + (size_t)d*512*HDIM, wgl + (size_t)d*512*HDIM,
        out_b + d*512, u, uth, utl);
  }

  ln_kernel<<<NROWS/8, 256, 0, stream>>>(u, ln_g, ln_b, unh, unl);
  head_tile<<<dim3(NROWS/128, 4), 256, 0, stream>>>(unh, unl, whh, whl, head_b, outp);
}